// Round 1
// baseline (1195.496 us; speedup 1.0000x reference)
//
#include <hip/hip_runtime.h>
#include <math.h>

#define D_MODEL 1024
#define NUM_HEADS 16
#define DK 64
#define BATCH 2
#define SEQ 2048
#define MROWS (BATCH * SEQ) /* 4096 */

// ---------------------------------------------------------------------------
// GEMM (NT): Y[M,1024] = X[M,1024] @ W[1024,1024]^T   (torch Linear convention)
// Both X rows and W rows are contiguous over k -> dot of two contiguous rows.
// BM=128, BN=64, BK=8, 256 threads, 8x4 micro-tile per thread.
// LDS stored k-major so compute reads are float4, conflict-free.
// ---------------------------------------------------------------------------
__global__ __launch_bounds__(256)
void gemm_nt_f32(const float* __restrict__ X, const float* __restrict__ W,
                 float* __restrict__ Y) {
    __shared__ float Xs[8][128];
    __shared__ float Ws[8][64];

    const int tid = threadIdx.x;
    const int tx = tid & 15;       // col group (4 cols)
    const int ty = tid >> 4;       // row group (4+4 rows)
    const int brow = blockIdx.y * 128;
    const int bcol = blockIdx.x * 64;

    float acc[8][4];
#pragma unroll
    for (int i = 0; i < 8; ++i)
#pragma unroll
        for (int j = 0; j < 4; ++j) acc[i][j] = 0.f;

    const int lr = tid >> 1;              // 0..127
    const int lk = (tid & 1) * 4;         // 0 or 4
    const float* xg = X + (size_t)(brow + lr) * D_MODEL + lk;
    const bool wload = (tid < 128);
    const int lrW = (tid & 127) >> 1;     // 0..63
    const int lkW = (tid & 1) * 4;
    const float* wg = W + (size_t)(bcol + lrW) * D_MODEL + lkW;

    for (int k0 = 0; k0 < D_MODEL; k0 += 8) {
        float4 xv = *(const float4*)(xg + k0);
        float4 wv = make_float4(0.f, 0.f, 0.f, 0.f);
        if (wload) wv = *(const float4*)(wg + k0);
        __syncthreads();  // previous iteration's compute reads done
        Xs[lk + 0][lr] = xv.x;
        Xs[lk + 1][lr] = xv.y;
        Xs[lk + 2][lr] = xv.z;
        Xs[lk + 3][lr] = xv.w;
        if (wload) {
            Ws[lkW + 0][lrW] = wv.x;
            Ws[lkW + 1][lrW] = wv.y;
            Ws[lkW + 2][lrW] = wv.z;
            Ws[lkW + 3][lrW] = wv.w;
        }
        __syncthreads();
#pragma unroll
        for (int k = 0; k < 8; ++k) {
            float4 a0 = *(const float4*)&Xs[k][ty * 4];
            float4 a1 = *(const float4*)&Xs[k][ty * 4 + 64];
            float4 bv = *(const float4*)&Ws[k][tx * 4];
            const float a[8] = {a0.x, a0.y, a0.z, a0.w, a1.x, a1.y, a1.z, a1.w};
            const float bb[4] = {bv.x, bv.y, bv.z, bv.w};
#pragma unroll
            for (int i = 0; i < 8; ++i)
#pragma unroll
                for (int j = 0; j < 4; ++j)
                    acc[i][j] = fmaf(a[i], bb[j], acc[i][j]);
        }
    }

#pragma unroll
    for (int ih = 0; ih < 2; ++ih)
#pragma unroll
        for (int i = 0; i < 4; ++i) {
            const int row = brow + ih * 64 + ty * 4 + i;
            float4 ov = make_float4(acc[ih * 4 + i][0], acc[ih * 4 + i][1],
                                    acc[ih * 4 + i][2], acc[ih * 4 + i][3]);
            *(float4*)&Y[(size_t)row * D_MODEL + bcol + tx * 4] = ov;
        }
}

// ---------------------------------------------------------------------------
// Flash-style attention, fp32. One block per (b, h, 64-row Q tile).
// Q,K kept d-major in LDS (conflict-free float4 fragment reads); P kept
// transposed [key][qrow] so PV needs one float4 read for 4 q-rows.
// Per-row softmax state (m,l) lives in registers, broadcast via __shfl.
// LDS = 4 * 16KB = 64KB exactly.
// ---------------------------------------------------------------------------
__global__ __launch_bounds__(256)
void attn_f32(const float* __restrict__ Q, const float* __restrict__ K,
              const float* __restrict__ V, float* __restrict__ A) {
    __shared__ float Qt[64][64];  // [d][qrow], pre-scaled by 1/8
    __shared__ float Kt[64][64];  // [d][krow]
    __shared__ float Vs[64][64];  // [krow][d]
    __shared__ float Pt[64][64];  // [krow][qrow]

    const int tid = threadIdx.x;
    const int tx = tid & 15;   // 4 output cols / 4 key cols
    const int ty = tid >> 4;   // 4 q rows
    const int lane = tid & 63;

    const int bid = blockIdx.x;           // qt(32) | h(16) | b(2)
    const int qt = bid & 31;
    const int h = (bid >> 5) & 15;
    const int b = bid >> 9;

    const size_t colbase = (size_t)h * DK;
    const int m0 = b * SEQ + qt * 64;  // global q-row base
    const int kvbase = b * SEQ;        // key/value row base

    // ---- load Q tile (transposed + scaled) ----
    {
        const float scale = 0.125f;  // 1/sqrt(64)
#pragma unroll
        for (int it = 0; it < 4; ++it) {
            const int idx = tid + it * 256;
            const int row = idx >> 4;
            const int c4 = (idx & 15) * 4;
            float4 qv = *(const float4*)&Q[(size_t)(m0 + row) * D_MODEL + colbase + c4];
            Qt[c4 + 0][row] = qv.x * scale;
            Qt[c4 + 1][row] = qv.y * scale;
            Qt[c4 + 2][row] = qv.z * scale;
            Qt[c4 + 3][row] = qv.w * scale;
        }
    }

    float o[4][4];
#pragma unroll
    for (int i = 0; i < 4; ++i)
#pragma unroll
        for (int j = 0; j < 4; ++j) o[i][j] = 0.f;

    float m_run = -INFINITY, l_run = 0.f;
    const int srow = ty * 4 + (tx >> 2);  // softmax row owned by this thread
    const int sq = (tx & 3) * 16;         // its 16-element segment

    for (int kt = 0; kt < SEQ / 64; ++kt) {
        // global loads (issued before the barrier to overlap the wait)
        float4 kv[4], vv[4];
#pragma unroll
        for (int it = 0; it < 4; ++it) {
            const int idx = tid + it * 256;
            const int row = idx >> 4;
            const int c4 = (idx & 15) * 4;
            const size_t g = (size_t)(kvbase + kt * 64 + row) * D_MODEL + colbase + c4;
            kv[it] = *(const float4*)&K[g];
            vv[it] = *(const float4*)&V[g];
        }
        __syncthreads();  // (A) prev PV reads of Kt/Vs finished (also Qt visible)
#pragma unroll
        for (int it = 0; it < 4; ++it) {
            const int idx = tid + it * 256;
            const int row = idx >> 4;
            const int c4 = (idx & 15) * 4;
            Kt[c4 + 0][row] = kv[it].x;
            Kt[c4 + 1][row] = kv[it].y;
            Kt[c4 + 2][row] = kv[it].z;
            Kt[c4 + 3][row] = kv[it].w;
            *(float4*)&Vs[row][c4] = vv[it];
        }
        __syncthreads();  // (B) staging visible

        // ---- scores: s[i][j] = sum_d Qt[d][ty*4+i] * Kt[d][tx*4+j] ----
        float s[4][4];
#pragma unroll
        for (int i = 0; i < 4; ++i)
#pragma unroll
            for (int j = 0; j < 4; ++j) s[i][j] = 0.f;
#pragma unroll 8
        for (int d = 0; d < 64; ++d) {
            float4 qv = *(const float4*)&Qt[d][ty * 4];
            float4 kk = *(const float4*)&Kt[d][tx * 4];
            const float qa[4] = {qv.x, qv.y, qv.z, qv.w};
            const float ka[4] = {kk.x, kk.y, kk.z, kk.w};
#pragma unroll
            for (int i = 0; i < 4; ++i)
#pragma unroll
                for (int j = 0; j < 4; ++j)
                    s[i][j] = fmaf(qa[i], ka[j], s[i][j]);
        }
        // store transposed: Pt[key][qrow]
#pragma unroll
        for (int j = 0; j < 4; ++j) {
            *(float4*)&Pt[tx * 4 + j][ty * 4] =
                make_float4(s[0][j], s[1][j], s[2][j], s[3][j]);
        }
        __syncthreads();  // (C) scores visible

        // ---- online softmax (4 threads per row, 16 elems each) ----
        float tmax = -INFINITY;
#pragma unroll
        for (int i = 0; i < 16; ++i) tmax = fmaxf(tmax, Pt[sq + i][srow]);
        tmax = fmaxf(tmax, __shfl_xor(tmax, 1));
        tmax = fmaxf(tmax, __shfl_xor(tmax, 2));
        const float mnew = fmaxf(m_run, tmax);
        const float alpha = __expf(m_run - mnew);  // exp(-inf)=0 on first tile
        float psum = 0.f;
#pragma unroll
        for (int i = 0; i < 16; ++i) {
            const float p = __expf(Pt[sq + i][srow] - mnew);
            Pt[sq + i][srow] = p;
            psum += p;
        }
        psum += __shfl_xor(psum, 1);
        psum += __shfl_xor(psum, 2);
        l_run = l_run * alpha + psum;
        m_run = mnew;
        __syncthreads();  // (D) exponentiated P visible

        // ---- rescale accumulator, then PV ----
#pragma unroll
        for (int i = 0; i < 4; ++i) {
            const float ai = __shfl(alpha, (lane & 48) | (i << 2));
            o[i][0] *= ai;
            o[i][1] *= ai;
            o[i][2] *= ai;
            o[i][3] *= ai;
        }
#pragma unroll 8
        for (int jk = 0; jk < 64; ++jk) {
            float4 pv = *(const float4*)&Pt[jk][ty * 4];
            float4 vv4 = *(const float4*)&Vs[jk][tx * 4];
            const float pa[4] = {pv.x, pv.y, pv.z, pv.w};
            const float va[4] = {vv4.x, vv4.y, vv4.z, vv4.w};
#pragma unroll
            for (int i = 0; i < 4; ++i)
#pragma unroll
                for (int j = 0; j < 4; ++j)
                    o[i][j] = fmaf(pa[i], va[j], o[i][j]);
        }
    }

    // ---- epilogue: divide by l, write A[b,s,h*64+d] ----
#pragma unroll
    for (int i = 0; i < 4; ++i) {
        const float li = __shfl(l_run, (lane & 48) | (i << 2));
        const float inv = 1.0f / li;
        const int row = m0 + ty * 4 + i;
        float4 ov = make_float4(o[i][0] * inv, o[i][1] * inv,
                                o[i][2] * inv, o[i][3] * inv);
        *(float4*)&A[(size_t)row * D_MODEL + colbase + tx * 4] = ov;
    }
}

// ---------------------------------------------------------------------------
extern "C" void kernel_launch(void* const* d_in, const int* in_sizes, int n_in,
                              void* d_out, int out_size, void* d_ws, size_t ws_size,
                              hipStream_t stream) {
    const float* query = (const float*)d_in[0];
    const float* key   = (const float*)d_in[1];
    const float* value = (const float*)d_in[2];
    const float* W_q   = (const float*)d_in[3];
    const float* W_k   = (const float*)d_in[4];
    const float* W_v   = (const float*)d_in[5];
    const float* W_o   = (const float*)d_in[6];
    float* out = (float*)d_out;

    float* ws = (float*)d_ws;
    const size_t plane = (size_t)MROWS * D_MODEL;  // 4096*1024 floats = 16.8 MB
    float* Qp = ws;
    float* Kp = ws + plane;
    float* Vp = ws + 2 * plane;
    float* Ap = ws + 3 * plane;  // needs 67.2 MB of workspace total

    dim3 gemm_grid(D_MODEL / 64, MROWS / 128);  // 16 x 32 = 512 blocks
    gemm_nt_f32<<<gemm_grid, 256, 0, stream>>>(query, W_q, Qp);
    gemm_nt_f32<<<gemm_grid, 256, 0, stream>>>(key,   W_k, Kp);
    gemm_nt_f32<<<gemm_grid, 256, 0, stream>>>(value, W_v, Vp);

    attn_f32<<<BATCH * NUM_HEADS * (SEQ / 64), 256, 0, stream>>>(Qp, Kp, Vp, Ap);

    gemm_nt_f32<<<gemm_grid, 256, 0, stream>>>(Ap, W_o, out);
}

// Round 2
// 209.233 us; speedup vs baseline: 5.7137x; 5.7137x over previous
//
#include <hip/hip_runtime.h>
#include <math.h>

typedef unsigned short ushort_t;
typedef __attribute__((ext_vector_type(8))) short short8;
typedef __attribute__((ext_vector_type(4))) float f32x4;
typedef __attribute__((ext_vector_type(4))) unsigned short ushort4v;

#define D_MODEL 1024
#define SEQ 2048
#define MROWS 4096
#define PLANE (MROWS * D_MODEL)    /* 4194304 elems */
#define WELEM (D_MODEL * D_MODEL)  /* 1048576 elems */

static __device__ __forceinline__ ushort_t f2bf(float f) {
    unsigned u = __builtin_bit_cast(unsigned, f);
    return (ushort_t)((u + 0x7fffu + ((u >> 16) & 1u)) >> 16);
}

// async global->LDS, 16B per lane; LDS dest = wave-uniform base + lane*16
#define GLDS16(gp, lp)                                                         \
    __builtin_amdgcn_global_load_lds(                                          \
        (const __attribute__((address_space(1))) void*)(gp),                   \
        (__attribute__((address_space(3))) void*)(lp), 16, 0, 0)

// ---------------------------------------------------------------------------
// fp32 -> bf16 conversion passes
// ---------------------------------------------------------------------------
__global__ __launch_bounds__(256)
void cvt_inputs(const float* __restrict__ q, const float* __restrict__ k,
                const float* __restrict__ v, ushort_t* __restrict__ dst) {
    const int p = blockIdx.x >> 11;  // 2048 blocks per plane
    const int i = ((blockIdx.x & 2047) * 256 + threadIdx.x) * 8;
    const float* s = (p == 0) ? q : (p == 1) ? k : v;
    ushort_t* d = dst + (size_t)p * PLANE;
    float4 a = *(const float4*)(s + i);
    float4 b = *(const float4*)(s + i + 4);
    short8 o;
    o[0] = (short)f2bf(a.x); o[1] = (short)f2bf(a.y);
    o[2] = (short)f2bf(a.z); o[3] = (short)f2bf(a.w);
    o[4] = (short)f2bf(b.x); o[5] = (short)f2bf(b.y);
    o[6] = (short)f2bf(b.z); o[7] = (short)f2bf(b.w);
    *(short8*)(d + i) = o;
}

__global__ __launch_bounds__(256)
void cvt_weights(const float* __restrict__ w0, const float* __restrict__ w1,
                 const float* __restrict__ w2, const float* __restrict__ w3,
                 ushort_t* __restrict__ dst) {
    const int p = blockIdx.x >> 9;  // 512 blocks per weight
    const int i = ((blockIdx.x & 511) * 256 + threadIdx.x) * 8;
    const float* s = (p == 0) ? w0 : (p == 1) ? w1 : (p == 2) ? w2 : w3;
    ushort_t* d = dst + (size_t)p * WELEM;
    float4 a = *(const float4*)(s + i);
    float4 b = *(const float4*)(s + i + 4);
    short8 o;
    o[0] = (short)f2bf(a.x); o[1] = (short)f2bf(a.y);
    o[2] = (short)f2bf(a.z); o[3] = (short)f2bf(a.w);
    o[4] = (short)f2bf(b.x); o[5] = (short)f2bf(b.y);
    o[6] = (short)f2bf(b.z); o[7] = (short)f2bf(b.w);
    *(short8*)(d + i) = o;
}

// ---------------------------------------------------------------------------
// bf16 MFMA GEMM (NT): C[M,N] = A[M,K] * B[N,K]^T, M=4096, N=K=1024.
// Tile 128x64, BK=64, 4 waves (2x2, each 64x32). fp32 accumulate.
// Staging via global_load_lds with pre-swizzled source; ds_read XOR-swizzled.
// OK: 0 = bf16 natural, 1 = f32 natural, 2 = bf16 transposed per-batch (V^T)
// ---------------------------------------------------------------------------
template <int OK>
__global__ __launch_bounds__(256)
void gemm_nt(const ushort_t* __restrict__ A, const ushort_t* __restrict__ B,
             void* __restrict__ Cp) {
    __shared__ __align__(16) ushort_t As[128 * 64];  // 16 KB, rows of 128B
    __shared__ __align__(16) ushort_t Bs[64 * 64];   // 8 KB

    const int tid = threadIdx.x;
    const int lane = tid & 63;
    const int wid = tid >> 6;
    const int wr = wid >> 1, wc = wid & 1;
    const int brow = blockIdx.y * 128;
    const int bcol = blockIdx.x * 64;

    const int lrow = lane >> 3;                  // row within 8-row chunk
    const int loff = ((lane & 7) ^ lrow) * 8;    // pre-swizzled elem offset

    const ushort_t* aSrc[4];
    const ushort_t* bSrc[2];
#pragma unroll
    for (int i = 0; i < 4; ++i)
        aSrc[i] = A + (size_t)(brow + (wid * 4 + i) * 8 + lrow) * D_MODEL + loff;
#pragma unroll
    for (int i = 0; i < 2; ++i)
        bSrc[i] = B + (size_t)(bcol + (wid * 2 + i) * 8 + lrow) * D_MODEL + loff;

    f32x4 acc[4][2];
#pragma unroll
    for (int i = 0; i < 4; ++i)
#pragma unroll
        for (int j = 0; j < 2; ++j) acc[i][j] = {0.f, 0.f, 0.f, 0.f};

    const int fr = lane & 15, fg = lane >> 4;

    for (int k0 = 0; k0 < D_MODEL; k0 += 64) {
        __syncthreads();  // prior frag reads done
#pragma unroll
        for (int i = 0; i < 4; ++i) GLDS16(aSrc[i] + k0, As + (wid * 4 + i) * 512);
#pragma unroll
        for (int i = 0; i < 2; ++i) GLDS16(bSrc[i] + k0, Bs + (wid * 2 + i) * 512);
        __syncthreads();  // staging visible (compiler drains vmcnt)
#pragma unroll
        for (int ks = 0; ks < 2; ++ks) {
            const int coff = (ks * 32 + fg * 8) ^ ((fr & 7) << 3);
            short8 af[4], bw[2];
#pragma unroll
            for (int mi = 0; mi < 4; ++mi)
                af[mi] = *(const short8*)&As[(wr * 64 + mi * 16 + fr) * 64 + coff];
#pragma unroll
            for (int nj = 0; nj < 2; ++nj)
                bw[nj] = *(const short8*)&Bs[(wc * 32 + nj * 16 + fr) * 64 + coff];
#pragma unroll
            for (int mi = 0; mi < 4; ++mi)
#pragma unroll
                for (int nj = 0; nj < 2; ++nj)
                    acc[mi][nj] = __builtin_amdgcn_mfma_f32_16x16x32_bf16(
                        af[mi], bw[nj], acc[mi][nj], 0, 0, 0);
        }
    }

    // epilogue: C layout col = lane&15, row = (lane>>4)*4 + reg
    if (OK == 0) {
        ushort_t* C = (ushort_t*)Cp;
#pragma unroll
        for (int mi = 0; mi < 4; ++mi)
#pragma unroll
            for (int nj = 0; nj < 2; ++nj) {
                const int n = bcol + wc * 32 + nj * 16 + fr;
#pragma unroll
                for (int r = 0; r < 4; ++r) {
                    const int m = brow + wr * 64 + mi * 16 + fg * 4 + r;
                    C[(size_t)m * D_MODEL + n] = f2bf(acc[mi][nj][r]);
                }
            }
    } else if (OK == 1) {
        float* C = (float*)Cp;
#pragma unroll
        for (int mi = 0; mi < 4; ++mi)
#pragma unroll
            for (int nj = 0; nj < 2; ++nj) {
                const int n = bcol + wc * 32 + nj * 16 + fr;
#pragma unroll
                for (int r = 0; r < 4; ++r) {
                    const int m = brow + wr * 64 + mi * 16 + fg * 4 + r;
                    C[(size_t)m * D_MODEL + n] = acc[mi][nj][r];
                }
            }
    } else {
        // V^T: store [b][n][s] with s = m % 2048, b = m / 2048 (4 rows pack to 8B)
        ushort_t* C = (ushort_t*)Cp;
#pragma unroll
        for (int mi = 0; mi < 4; ++mi)
#pragma unroll
            for (int nj = 0; nj < 2; ++nj) {
                const int n = bcol + wc * 32 + nj * 16 + fr;
                const int m0 = brow + wr * 64 + mi * 16 + fg * 4;
                ushort4v o4;
#pragma unroll
                for (int r = 0; r < 4; ++r) o4[r] = f2bf(acc[mi][nj][r]);
                *(ushort4v*)&C[((size_t)(m0 >> 11) << 21) + (size_t)n * SEQ + (m0 & 2047)] = o4;
            }
    }
}

// ---------------------------------------------------------------------------
// bf16 MFMA flash attention. 1024 blocks (b,h,qt), 256 thr = 4 waves.
// Wave owns 16 q-rows; KV tile 64. Q/K/V staged via global_load_lds with
// pre-swizzled source; softmax in registers; P via per-wave LDS as bf16.
// V arrives pre-transposed ([b][d_global][s]) so PV B-reads are contiguous.
// ---------------------------------------------------------------------------
__global__ __launch_bounds__(256)
void attn_mfma(const ushort_t* __restrict__ Qp, const ushort_t* __restrict__ Kp,
               const ushort_t* __restrict__ VT, ushort_t* __restrict__ Ap) {
    __shared__ __align__(16) ushort_t Qs[64 * 64];       // 8 KB
    __shared__ __align__(16) ushort_t Ks[64 * 64];       // 8 KB
    __shared__ __align__(16) ushort_t Vs[64 * 64];       // 8 KB (d-major)
    __shared__ __align__(16) ushort_t Ps[4 * 16 * 64];   // 8 KB, per-wave

    const int tid = threadIdx.x;
    const int lane = tid & 63;
    const int wid = tid >> 6;
    const int bid = blockIdx.x;
    const int qt = bid & 31;
    const int h = (bid >> 5) & 15;
    const int b = bid >> 9;

    const int lrow = lane >> 3;
    const int loff = ((lane & 7) ^ lrow) * 8;
    const int fr = lane & 15, fg = lane >> 4;

    const ushort_t* qSrc[2];
    const ushort_t* kSrc[2];
    const ushort_t* vSrc[2];
#pragma unroll
    for (int j = 0; j < 2; ++j) {
        const int cr = (wid * 2 + j) * 8 + lrow;
        qSrc[j] = Qp + (size_t)(b * SEQ + qt * 64 + cr) * D_MODEL + h * 64 + loff;
        kSrc[j] = Kp + (size_t)(b * SEQ + cr) * D_MODEL + h * 64 + loff;
        vSrc[j] = VT + ((size_t)b << 21) + (size_t)(h * 64 + cr) * SEQ + loff;
    }

    // stage Q once
#pragma unroll
    for (int j = 0; j < 2; ++j) GLDS16(qSrc[j], Qs + (wid * 2 + j) * 512);
    __syncthreads();

    short8 aq[2];
#pragma unroll
    for (int ks = 0; ks < 2; ++ks)
        aq[ks] = *(const short8*)&Qs[(wid * 16 + fr) * 64 +
                                     ((ks * 32 + fg * 8) ^ ((fr & 7) << 3))];

    f32x4 accO[4];
#pragma unroll
    for (int nd = 0; nd < 4; ++nd) accO[nd] = {0.f, 0.f, 0.f, 0.f};
    float rowm[4], rowl[4];
#pragma unroll
    for (int r = 0; r < 4; ++r) { rowm[r] = -INFINITY; rowl[r] = 0.f; }

    const float CEXP = 0.18033688011112042f;  // log2(e) / sqrt(64)

    for (int kt = 0; kt < SEQ / 64; ++kt) {
        __syncthreads();  // prior tile's K/V reads done
#pragma unroll
        for (int j = 0; j < 2; ++j) {
            GLDS16(kSrc[j], Ks + (wid * 2 + j) * 512);
            GLDS16(vSrc[j], Vs + (wid * 2 + j) * 512);
            kSrc[j] += 64 * D_MODEL;
            vSrc[j] += 64;
        }
        __syncthreads();  // staging visible

        // ---- scores: wave's 16 q-rows x 64 keys ----
        f32x4 accS[4];
#pragma unroll
        for (int n = 0; n < 4; ++n) accS[n] = {0.f, 0.f, 0.f, 0.f};
#pragma unroll
        for (int ks = 0; ks < 2; ++ks) {
            const int coff = (ks * 32 + fg * 8) ^ ((fr & 7) << 3);
#pragma unroll
            for (int n = 0; n < 4; ++n) {
                short8 bk = *(const short8*)&Ks[(n * 16 + fr) * 64 + coff];
                accS[n] = __builtin_amdgcn_mfma_f32_16x16x32_bf16(aq[ks], bk, accS[n], 0, 0, 0);
            }
        }

        // ---- online softmax (row r lives in 16 lanes of group fg) ----
#pragma unroll
        for (int r = 0; r < 4; ++r) {
            float t = fmaxf(fmaxf(accS[0][r], accS[1][r]),
                            fmaxf(accS[2][r], accS[3][r]));
            t = fmaxf(t, __shfl_xor(t, 1));
            t = fmaxf(t, __shfl_xor(t, 2));
            t = fmaxf(t, __shfl_xor(t, 4));
            t = fmaxf(t, __shfl_xor(t, 8));
            const float mnew = fmaxf(rowm[r], t);
            const float al = exp2f((rowm[r] - mnew) * CEXP);
            rowm[r] = mnew;
            float ps = 0.f;
#pragma unroll
            for (int n = 0; n < 4; ++n) {
                const float p = exp2f((accS[n][r] - mnew) * CEXP);
                accS[n][r] = p;
                ps += p;
            }
            ps += __shfl_xor(ps, 1);
            ps += __shfl_xor(ps, 2);
            ps += __shfl_xor(ps, 4);
            ps += __shfl_xor(ps, 8);
            rowl[r] = rowl[r] * al + ps;
#pragma unroll
            for (int nd = 0; nd < 4; ++nd) accO[nd][r] *= al;
        }

        // ---- P -> bf16 -> per-wave LDS (swizzled) ----
#pragma unroll
        for (int r = 0; r < 4; ++r) {
            const int q = fg * 4 + r;
            const int base = wid * 1024 + q * 64;
            const int xr = (q & 7) << 3;
#pragma unroll
            for (int n = 0; n < 4; ++n)
                Ps[base + ((n * 16 + fr) ^ xr)] = f2bf(accS[n][r]);
        }

        // ---- PV ----
#pragma unroll
        for (int ks = 0; ks < 2; ++ks) {
            const int coff = (ks * 32 + fg * 8) ^ ((fr & 7) << 3);
            short8 ap = *(const short8*)&Ps[wid * 1024 + fr * 64 + coff];
#pragma unroll
            for (int nd = 0; nd < 4; ++nd) {
                short8 bv = *(const short8*)&Vs[(nd * 16 + fr) * 64 + coff];
                accO[nd] = __builtin_amdgcn_mfma_f32_16x16x32_bf16(ap, bv, accO[nd], 0, 0, 0);
            }
        }
    }

    // ---- epilogue ----
    const int qg = b * SEQ + qt * 64 + wid * 16 + fg * 4;
#pragma unroll
    for (int r = 0; r < 4; ++r) {
        const float inv = 1.0f / rowl[r];
#pragma unroll
        for (int nd = 0; nd < 4; ++nd)
            Ap[(size_t)(qg + r) * D_MODEL + h * 64 + nd * 16 + fr] =
                f2bf(accO[nd][r] * inv);
    }
}

// ---------------------------------------------------------------------------
extern "C" void kernel_launch(void* const* d_in, const int* in_sizes, int n_in,
                              void* d_out, int out_size, void* d_ws, size_t ws_size,
                              hipStream_t stream) {
    const float* query = (const float*)d_in[0];
    const float* key   = (const float*)d_in[1];
    const float* value = (const float*)d_in[2];
    const float* W_q   = (const float*)d_in[3];
    const float* W_k   = (const float*)d_in[4];
    const float* W_v   = (const float*)d_in[5];
    const float* W_o   = (const float*)d_in[6];
    float* out = (float*)d_out;

    ushort_t* ws = (ushort_t*)d_ws;
    ushort_t* Xq = ws;                               // 3 bf16 input planes
    ushort_t* Wb = ws + 3 * (size_t)PLANE;           // 4 bf16 weights
    ushort_t* Qp = ws + 4 * (size_t)PLANE;           // Q proj (natural)
    ushort_t* Kp = Qp + (size_t)PLANE;               // K proj (natural)
    ushort_t* VT = Kp + (size_t)PLANE;               // V proj (transposed)
    ushort_t* Ap = VT + (size_t)PLANE;               // attention out (natural)
    // total 8 * PLANE * 2B = 67.1 MB

    cvt_inputs<<<6144, 256, 0, stream>>>(query, key, value, Xq);
    cvt_weights<<<2048, 256, 0, stream>>>(W_q, W_k, W_v, W_o, Wb);

    dim3 gg(D_MODEL / 64, MROWS / 128);  // (16, 32) = 512 blocks
    gemm_nt<0><<<gg, 256, 0, stream>>>(Xq,                Wb + 0 * (size_t)WELEM, Qp);
    gemm_nt<0><<<gg, 256, 0, stream>>>(Xq + (size_t)PLANE, Wb + 1 * (size_t)WELEM, Kp);
    gemm_nt<2><<<gg, 256, 0, stream>>>(Xq + 2 * (size_t)PLANE, Wb + 2 * (size_t)WELEM, VT);

    attn_mfma<<<1024, 256, 0, stream>>>(Qp, Kp, VT, Ap);

    gemm_nt<1><<<gg, 256, 0, stream>>>(Ap, Wb + 3 * (size_t)WELEM, out);
}

// Round 3
// 181.796 us; speedup vs baseline: 6.5760x; 1.1509x over previous
//
#include <hip/hip_runtime.h>
#include <hip/hip_bf16.h>
#include <math.h>

typedef unsigned short ushort_t;
typedef __attribute__((ext_vector_type(8))) short short8;
typedef __attribute__((ext_vector_type(4))) float f32x4;
typedef __attribute__((ext_vector_type(4))) unsigned short ushort4v;

#define D_MODEL 1024
#define SEQ 2048
#define MROWS 4096
#define PLANE (MROWS * D_MODEL)    /* 4194304 elems */
#define WELEM (D_MODEL * D_MODEL)  /* 1048576 elems */

static __device__ __forceinline__ ushort_t f2bf(float f) {
    return __builtin_bit_cast(ushort_t, __float2bfloat16(f));
}

// async global->LDS, 16B per lane; LDS dest = wave-uniform base + lane*16
#define GLDS16(gp, lp)                                                         \
    __builtin_amdgcn_global_load_lds(                                          \
        (const __attribute__((address_space(1))) void*)(gp),                   \
        (__attribute__((address_space(3))) void*)(lp), 16, 0, 0)

// ---------------------------------------------------------------------------
// fp32 -> bf16 conversion passes
// ---------------------------------------------------------------------------
__global__ __launch_bounds__(256)
void cvt_inputs(const float* __restrict__ q, const float* __restrict__ k,
                const float* __restrict__ v, ushort_t* __restrict__ dst) {
    const int p = blockIdx.x >> 11;  // 2048 blocks per plane
    const int i = ((blockIdx.x & 2047) * 256 + threadIdx.x) * 8;
    const float* s = (p == 0) ? q : (p == 1) ? k : v;
    ushort_t* d = dst + (size_t)p * PLANE;
    float4 a = *(const float4*)(s + i);
    float4 b = *(const float4*)(s + i + 4);
    short8 o;
    o[0] = (short)f2bf(a.x); o[1] = (short)f2bf(a.y);
    o[2] = (short)f2bf(a.z); o[3] = (short)f2bf(a.w);
    o[4] = (short)f2bf(b.x); o[5] = (short)f2bf(b.y);
    o[6] = (short)f2bf(b.z); o[7] = (short)f2bf(b.w);
    *(short8*)(d + i) = o;
}

__global__ __launch_bounds__(256)
void cvt_weights(const float* __restrict__ w0, const float* __restrict__ w1,
                 const float* __restrict__ w2, const float* __restrict__ w3,
                 ushort_t* __restrict__ dst) {
    const int p = blockIdx.x >> 9;  // 512 blocks per weight
    const int i = ((blockIdx.x & 511) * 256 + threadIdx.x) * 8;
    const float* s = (p == 0) ? w0 : (p == 1) ? w1 : (p == 2) ? w2 : w3;
    ushort_t* d = dst + (size_t)p * WELEM;
    float4 a = *(const float4*)(s + i);
    float4 b = *(const float4*)(s + i + 4);
    short8 o;
    o[0] = (short)f2bf(a.x); o[1] = (short)f2bf(a.y);
    o[2] = (short)f2bf(a.z); o[3] = (short)f2bf(a.w);
    o[4] = (short)f2bf(b.x); o[5] = (short)f2bf(b.y);
    o[6] = (short)f2bf(b.z); o[7] = (short)f2bf(b.w);
    *(short8*)(d + i) = o;
}

// ---------------------------------------------------------------------------
// bf16 MFMA GEMM (NT): C[M,N] = A[M,K] * B[N,K]^T, M=4096, N=K=1024.
// Tile 128x64, BK=64, 4 waves (2x2, each 64x32), fp32 accumulate.
// Double-buffered LDS: one __syncthreads per K-step, prefetch issued after.
// OK: 0 = bf16 natural, 1 = f32 natural, 2 = bf16 transposed per-batch (V^T)
// ---------------------------------------------------------------------------
template <int OK>
__global__ __launch_bounds__(256)
void gemm_nt(const ushort_t* __restrict__ A, const ushort_t* __restrict__ B,
             void* __restrict__ Cp) {
    __shared__ __align__(16) ushort_t As[2][128 * 64];  // 32 KB
    __shared__ __align__(16) ushort_t Bs[2][64 * 64];   // 16 KB

    const int tid = threadIdx.x;
    const int lane = tid & 63;
    const int wid = tid >> 6;
    const int wr = wid >> 1, wc = wid & 1;
    const int brow = blockIdx.y * 128;
    const int bcol = blockIdx.x * 64;

    const int lrow = lane >> 3;                  // row within 8-row chunk
    const int loff = ((lane & 7) ^ lrow) * 8;    // pre-swizzled elem offset

    const ushort_t* aSrc[4];
    const ushort_t* bSrc[2];
#pragma unroll
    for (int i = 0; i < 4; ++i)
        aSrc[i] = A + (size_t)(brow + (wid * 4 + i) * 8 + lrow) * D_MODEL + loff;
#pragma unroll
    for (int i = 0; i < 2; ++i)
        bSrc[i] = B + (size_t)(bcol + (wid * 2 + i) * 8 + lrow) * D_MODEL + loff;

    f32x4 acc[4][2];
#pragma unroll
    for (int i = 0; i < 4; ++i)
#pragma unroll
        for (int j = 0; j < 2; ++j) acc[i][j] = {0.f, 0.f, 0.f, 0.f};

    const int fr = lane & 15, fg = lane >> 4;

    // prologue: stage k0=0 into buf 0
#pragma unroll
    for (int i = 0; i < 4; ++i) GLDS16(aSrc[i], As[0] + (wid * 4 + i) * 512);
#pragma unroll
    for (int i = 0; i < 2; ++i) GLDS16(bSrc[i], Bs[0] + (wid * 2 + i) * 512);

    int cur = 0;
    for (int k0 = 0; k0 < D_MODEL; k0 += 64) {
        __syncthreads();  // drains vmcnt(0): tile-k0 staging visible
        if (k0 + 64 < D_MODEL) {
#pragma unroll
            for (int i = 0; i < 4; ++i)
                GLDS16(aSrc[i] + k0 + 64, As[cur ^ 1] + (wid * 4 + i) * 512);
#pragma unroll
            for (int i = 0; i < 2; ++i)
                GLDS16(bSrc[i] + k0 + 64, Bs[cur ^ 1] + (wid * 2 + i) * 512);
        }
#pragma unroll
        for (int ks = 0; ks < 2; ++ks) {
            const int coff = (ks * 32 + fg * 8) ^ ((fr & 7) << 3);
            short8 af[4], bw[2];
#pragma unroll
            for (int mi = 0; mi < 4; ++mi)
                af[mi] = *(const short8*)&As[cur][(wr * 64 + mi * 16 + fr) * 64 + coff];
#pragma unroll
            for (int nj = 0; nj < 2; ++nj)
                bw[nj] = *(const short8*)&Bs[cur][(wc * 32 + nj * 16 + fr) * 64 + coff];
#pragma unroll
            for (int mi = 0; mi < 4; ++mi)
#pragma unroll
                for (int nj = 0; nj < 2; ++nj)
                    acc[mi][nj] = __builtin_amdgcn_mfma_f32_16x16x32_bf16(
                        af[mi], bw[nj], acc[mi][nj], 0, 0, 0);
        }
        cur ^= 1;
    }

    // epilogue: C layout col = lane&15, row = (lane>>4)*4 + reg
    if (OK == 0) {
        ushort_t* C = (ushort_t*)Cp;
#pragma unroll
        for (int mi = 0; mi < 4; ++mi)
#pragma unroll
            for (int nj = 0; nj < 2; ++nj) {
                const int n = bcol + wc * 32 + nj * 16 + fr;
#pragma unroll
                for (int r = 0; r < 4; ++r) {
                    const int m = brow + wr * 64 + mi * 16 + fg * 4 + r;
                    C[(size_t)m * D_MODEL + n] = f2bf(acc[mi][nj][r]);
                }
            }
    } else if (OK == 1) {
        float* C = (float*)Cp;
#pragma unroll
        for (int mi = 0; mi < 4; ++mi)
#pragma unroll
            for (int nj = 0; nj < 2; ++nj) {
                const int n = bcol + wc * 32 + nj * 16 + fr;
#pragma unroll
                for (int r = 0; r < 4; ++r) {
                    const int m = brow + wr * 64 + mi * 16 + fg * 4 + r;
                    C[(size_t)m * D_MODEL + n] = acc[mi][nj][r];
                }
            }
    } else {
        // V^T: store [b][n][s] with s = m % 2048, b = m / 2048 (4 rows pack to 8B)
        ushort_t* C = (ushort_t*)Cp;
#pragma unroll
        for (int mi = 0; mi < 4; ++mi)
#pragma unroll
            for (int nj = 0; nj < 2; ++nj) {
                const int n = bcol + wc * 32 + nj * 16 + fr;
                const int m0 = brow + wr * 64 + mi * 16 + fg * 4;
                ushort4v o4;
#pragma unroll
                for (int r = 0; r < 4; ++r) o4[r] = f2bf(acc[mi][nj][r]);
                *(ushort4v*)&C[((size_t)(m0 >> 11) << 21) + (size_t)n * SEQ + (m0 & 2047)] = o4;
            }
    }
}

// ---------------------------------------------------------------------------
// bf16 MFMA flash attention, swapped-QK^T + defer-max + 2-phase K/V dbuf.
// 1024 blocks (b,h,qt), 256 thr = 4 waves; wave owns 16 q-rows; KV tile 64.
// Swapped QK^T (mfma(K,Q)) puts one q-row's 16 scores in each lane:
// softmax reduce = 15 in-lane fmax + 2 shfl_xor; P packs to 4 ds_write_b64.
// LDS: K dbuf 16K + V dbuf 16K + P/Q region 8K = 40 KB -> 4 blocks/CU.
// ---------------------------------------------------------------------------
__global__ __launch_bounds__(256)
void attn_mfma(const ushort_t* __restrict__ Qp, const ushort_t* __restrict__ Kp,
               const ushort_t* __restrict__ VT, ushort_t* __restrict__ Ap) {
    __shared__ __align__(16) ushort_t Ks[2][64 * 64];   // 16 KB
    __shared__ __align__(16) ushort_t Vs[2][64 * 64];   // 16 KB (d-major)
    __shared__ __align__(16) ushort_t Ps[4 * 16 * 64];  // 8 KB: Q at start, then P

    const int tid = threadIdx.x;
    const int lane = tid & 63;
    const int wid = tid >> 6;
    const int bid = blockIdx.x;
    const int qt = bid & 31;
    const int h = (bid >> 5) & 15;
    const int b = bid >> 9;

    const int lrow = lane >> 3;
    const int loff = ((lane & 7) ^ lrow) * 8;
    const int fr = lane & 15, fg = lane >> 4;

    const ushort_t* kS[2];
    const ushort_t* vS[2];
#pragma unroll
    for (int j = 0; j < 2; ++j) {
        const int cr = (wid * 2 + j) * 8 + lrow;
        const ushort_t* qS =
            Qp + (size_t)(b * SEQ + qt * 64 + cr) * D_MODEL + h * 64 + loff;
        kS[j] = Kp + (size_t)(b * SEQ + cr) * D_MODEL + h * 64 + loff;
        vS[j] = VT + ((size_t)b << 21) + (size_t)(h * 64 + cr) * SEQ + loff;
        GLDS16(qS, Ps + (wid * 2 + j) * 512);       // Q -> own wave's P region
        GLDS16(kS[j], Ks[0] + (wid * 2 + j) * 512); // K tile 0
        GLDS16(vS[j], Vs[0] + (wid * 2 + j) * 512); // V tile 0
        kS[j] += 64 * D_MODEL;
        vS[j] += 64;
    }
    __syncthreads();  // drains vmcnt: Q/K0/V0 visible

    short8 aq[2];
#pragma unroll
    for (int ks = 0; ks < 2; ++ks)
        aq[ks] = *(const short8*)&Ps[(wid * 16 + fr) * 64 +
                                     ((ks * 32 + fg * 8) ^ ((fr & 7) << 3))];

    f32x4 accO[4];
#pragma unroll
    for (int nd = 0; nd < 4; ++nd) accO[nd] = {0.f, 0.f, 0.f, 0.f};
    float rowm = -INFINITY, rowl = 0.f;  // this lane owns q-row (wid*16 + fr)

    const float CEXP = 0.18033688011112042f;  // log2(e) / sqrt(64)
    const float THR = 8.317766166719343f;     // 1.5 / CEXP  (P bounded by 2^1.5)

    int cur = 0;
    for (int kt = 0; kt < SEQ / 64; ++kt) {
        __syncthreads();  // tile-kt staging visible; all waves done with buf^1
        if (kt + 1 < SEQ / 64) {
#pragma unroll
            for (int j = 0; j < 2; ++j) {
                GLDS16(kS[j], Ks[cur ^ 1] + (wid * 2 + j) * 512);
                GLDS16(vS[j], Vs[cur ^ 1] + (wid * 2 + j) * 512);
                kS[j] += 64 * D_MODEL;
                vS[j] += 64;
            }
        }

        // ---- swapped scores: S[key][q], lane holds q=fr, keys n*16+fg*4+r ----
        f32x4 accS[4];
#pragma unroll
        for (int n = 0; n < 4; ++n) accS[n] = {0.f, 0.f, 0.f, 0.f};
#pragma unroll
        for (int ks = 0; ks < 2; ++ks) {
            const int coff = (ks * 32 + fg * 8) ^ ((fr & 7) << 3);
#pragma unroll
            for (int n = 0; n < 4; ++n) {
                short8 ak = *(const short8*)&Ks[cur][(n * 16 + fr) * 64 + coff];
                accS[n] = __builtin_amdgcn_mfma_f32_16x16x32_bf16(ak, aq[ks], accS[n], 0, 0, 0);
            }
        }

        // ---- online softmax: in-lane 16-max + 2 shfl, defer-max rescale ----
        float mx = accS[0][0];
#pragma unroll
        for (int n = 0; n < 4; ++n)
#pragma unroll
            for (int r = 0; r < 4; ++r) mx = fmaxf(mx, accS[n][r]);
        mx = fmaxf(mx, __shfl_xor(mx, 16));
        mx = fmaxf(mx, __shfl_xor(mx, 32));
        if (__any(mx > rowm + THR)) {
            const float mnew = fmaxf(rowm, mx);
            const float al = exp2f((rowm - mnew) * CEXP);  // 0 on first tile
            rowm = mnew;
            rowl *= al;
#pragma unroll
            for (int r = 0; r < 4; ++r) {
                const float ar = __shfl(al, (lane & 48) | ((fg << 2) + r));
#pragma unroll
                for (int nd = 0; nd < 4; ++nd) accO[nd][r] *= ar;
            }
        }
        float ps = 0.f;
#pragma unroll
        for (int n = 0; n < 4; ++n)
#pragma unroll
            for (int r = 0; r < 4; ++r) {
                const float p = exp2f((accS[n][r] - rowm) * CEXP);
                accS[n][r] = p;
                ps += p;
            }
        ps += __shfl_xor(ps, 16);
        ps += __shfl_xor(ps, 32);
        rowl += ps;

        // ---- P -> bf16, 4x ds_write_b64 into own wave region (swizzled) ----
#pragma unroll
        for (int n = 0; n < 4; ++n) {
            ushort4v o4;
#pragma unroll
            for (int r = 0; r < 4; ++r) o4[r] = f2bf(accS[n][r]);
            const int w = (n * 4 + fg) ^ (fr & 14);
            *(ushort4v*)&Ps[wid * 1024 + fr * 64 + w * 4] = o4;
        }

        // ---- PV: O[q][d] = P[q][k] V^T[d][k] ----
#pragma unroll
        for (int ks = 0; ks < 2; ++ks) {
            const int pw = ((ks * 8 + fg * 2) ^ (fr & 14)) * 4;
            short8 ap = *(const short8*)&Ps[wid * 1024 + fr * 64 + pw];
            const int coff = (ks * 32 + fg * 8) ^ ((fr & 7) << 3);
#pragma unroll
            for (int nd = 0; nd < 4; ++nd) {
                short8 bv = *(const short8*)&Vs[cur][(nd * 16 + fr) * 64 + coff];
                accO[nd] = __builtin_amdgcn_mfma_f32_16x16x32_bf16(ap, bv, accO[nd], 0, 0, 0);
            }
        }
        cur ^= 1;
    }

    // ---- epilogue: lane holds O[q=fg*4+r][d=nd*16+fr]; l lives at lane fr=q ----
#pragma unroll
    for (int r = 0; r < 4; ++r) {
        const float lq = __shfl(rowl, (lane & 48) | ((fg << 2) + r));
        const float inv = 1.0f / lq;
        const int row = b * SEQ + qt * 64 + wid * 16 + (fg << 2) + r;
#pragma unroll
        for (int nd = 0; nd < 4; ++nd)
            Ap[(size_t)row * D_MODEL + h * 64 + nd * 16 + fr] =
                f2bf(accO[nd][r] * inv);
    }
}

// ---------------------------------------------------------------------------
extern "C" void kernel_launch(void* const* d_in, const int* in_sizes, int n_in,
                              void* d_out, int out_size, void* d_ws, size_t ws_size,
                              hipStream_t stream) {
    const float* query = (const float*)d_in[0];
    const float* key   = (const float*)d_in[1];
    const float* value = (const float*)d_in[2];
    const float* W_q   = (const float*)d_in[3];
    const float* W_k   = (const float*)d_in[4];
    const float* W_v   = (const float*)d_in[5];
    const float* W_o   = (const float*)d_in[6];
    float* out = (float*)d_out;

    ushort_t* ws = (ushort_t*)d_ws;
    ushort_t* Xq = ws;                               // 3 bf16 input planes
    ushort_t* Wb = ws + 3 * (size_t)PLANE;           // 4 bf16 weights
    ushort_t* Qp = ws + 4 * (size_t)PLANE;           // Q proj (natural)
    ushort_t* Kp = Qp + (size_t)PLANE;               // K proj (natural)
    ushort_t* VT = Kp + (size_t)PLANE;               // V proj (transposed)
    ushort_t* Ap = VT + (size_t)PLANE;               // attention out (natural)
    // total 8 * PLANE * 2B = 67.1 MB

    cvt_inputs<<<6144, 256, 0, stream>>>(query, key, value, Xq);
    cvt_weights<<<2048, 256, 0, stream>>>(W_q, W_k, W_v, W_o, Wb);

    dim3 gg(D_MODEL / 64, MROWS / 128);  // (16, 32) = 512 blocks
    gemm_nt<0><<<gg, 256, 0, stream>>>(Xq,                    Wb + 0 * (size_t)WELEM, Qp);
    gemm_nt<0><<<gg, 256, 0, stream>>>(Xq + (size_t)PLANE,    Wb + 1 * (size_t)WELEM, Kp);
    gemm_nt<2><<<gg, 256, 0, stream>>>(Xq + 2 * (size_t)PLANE, Wb + 2 * (size_t)WELEM, VT);

    attn_mfma<<<1024, 256, 0, stream>>>(Qp, Kp, VT, Ap);

    gemm_nt<1><<<gg, 256, 0, stream>>>(Ap, Wb + 3 * (size_t)WELEM, out);
}

// Round 4
// 140.890 us; speedup vs baseline: 8.4853x; 1.2903x over previous
//
#include <hip/hip_runtime.h>
#include <math.h>

typedef unsigned short ushort_t;
typedef __attribute__((ext_vector_type(8))) short short8;
typedef __attribute__((ext_vector_type(4))) float f32x4;
typedef __attribute__((ext_vector_type(4))) unsigned short ushort4v;
typedef __attribute__((ext_vector_type(2))) unsigned int uint2v;

#define D_MODEL 1024
#define SEQ 2048
#define MROWS 4096
#define PLANE (MROWS * D_MODEL)    /* 4194304 elems */
#define WELEM (D_MODEL * D_MODEL)  /* 1048576 elems */

static __device__ __forceinline__ ushort_t f2bf(float f) {
    unsigned u = __builtin_bit_cast(unsigned, f);
    return (ushort_t)((u + 0x7fffu + ((u >> 16) & 1u)) >> 16);
}
static __device__ __forceinline__ unsigned cvtpk(float lo, float hi) {
    unsigned r;
    asm("v_cvt_pk_bf16_f32 %0, %1, %2" : "=v"(r) : "v"(lo), "v"(hi));
    return r;
}

// async global->LDS, 16B per lane; LDS dest = wave-uniform base + lane*16
#define GLDS16(gp, lp)                                                         \
    __builtin_amdgcn_global_load_lds(                                          \
        (const __attribute__((address_space(1))) void*)(gp),                   \
        (__attribute__((address_space(3))) void*)(lp), 16, 0, 0)

// ---------------------------------------------------------------------------
// fp32 -> bf16: all 7 tensors in one launch.
// blocks 0..6143: q/k/v (2048 each); 6144..8191: w0..w3 (512 each)
// ---------------------------------------------------------------------------
__global__ __launch_bounds__(256)
void cvt_all(const float* __restrict__ q, const float* __restrict__ k,
             const float* __restrict__ v, const float* __restrict__ w0,
             const float* __restrict__ w1, const float* __restrict__ w2,
             const float* __restrict__ w3, ushort_t* __restrict__ dst) {
    int blk = blockIdx.x;
    const float* s;
    size_t base;
    if (blk < 6144) {
        const int p = blk >> 11;
        s = (p == 0) ? q : (p == 1) ? k : v;
        base = (size_t)p * PLANE;
        blk &= 2047;
    } else {
        const int p = (blk - 6144) >> 9;
        s = (p == 0) ? w0 : (p == 1) ? w1 : (p == 2) ? w2 : w3;
        base = 3 * (size_t)PLANE + (size_t)p * WELEM;
        blk = (blk - 6144) & 511;
    }
    const int i = (blk * 256 + threadIdx.x) * 8;
    float4 a = *(const float4*)(s + i);
    float4 bb = *(const float4*)(s + i + 4);
    short8 o;
    o[0] = (short)f2bf(a.x); o[1] = (short)f2bf(a.y);
    o[2] = (short)f2bf(a.z); o[3] = (short)f2bf(a.w);
    o[4] = (short)f2bf(bb.x); o[5] = (short)f2bf(bb.y);
    o[6] = (short)f2bf(bb.z); o[7] = (short)f2bf(bb.w);
    *(short8*)(dst + base + i) = o;
}

// ---------------------------------------------------------------------------
// Projection GEMM x3 in one launch (z = 0:Q, 1:K, 2:V-transposed).
// m97 structure: 128x128 tile, BK=64, 4 waves (2x2, each 64x64),
// single-buffer LDS (32 KB) + 2 barriers per K-step, 3 blocks/CU.
// ---------------------------------------------------------------------------
__global__ __launch_bounds__(256)
void gemm3(const ushort_t* __restrict__ Xq, const ushort_t* __restrict__ Wb,
           ushort_t* __restrict__ Cb) {
    __shared__ __align__(16) ushort_t As[128 * 64];  // 16 KB
    __shared__ __align__(16) ushort_t Bs[128 * 64];  // 16 KB

    const int z = blockIdx.z;
    const ushort_t* A = Xq + (size_t)z * PLANE;
    const ushort_t* B = Wb + (size_t)z * WELEM;
    ushort_t* C = Cb + (size_t)z * PLANE;

    const int tid = threadIdx.x;
    const int lane = tid & 63;
    const int wid = tid >> 6;
    const int wr = wid >> 1, wc = wid & 1;
    const int brow = blockIdx.y * 128;
    const int bcol = blockIdx.x * 128;

    const int lrow = lane >> 3;
    const int loff = ((lane & 7) ^ lrow) * 8;  // pre-swizzled source offset

    const ushort_t* aS[4];
    const ushort_t* bS[4];
#pragma unroll
    for (int i = 0; i < 4; ++i) {
        aS[i] = A + (size_t)(brow + wid * 32 + i * 8 + lrow) * D_MODEL + loff;
        bS[i] = B + (size_t)(bcol + wid * 32 + i * 8 + lrow) * D_MODEL + loff;
    }

    f32x4 acc[4][4];
#pragma unroll
    for (int i = 0; i < 4; ++i)
#pragma unroll
        for (int j = 0; j < 4; ++j) acc[i][j] = {0.f, 0.f, 0.f, 0.f};

    const int fr = lane & 15, fg = lane >> 4;

    for (int k0 = 0; k0 < D_MODEL; k0 += 64) {
        __syncthreads();  // prior frag reads done
#pragma unroll
        for (int i = 0; i < 4; ++i) {
            GLDS16(aS[i] + k0, As + (wid * 32 + i * 8) * 64);
            GLDS16(bS[i] + k0, Bs + (wid * 32 + i * 8) * 64);
        }
        __syncthreads();  // staging landed (vmcnt drained before barrier)
#pragma unroll
        for (int ks = 0; ks < 2; ++ks) {
            const int coff = (ks * 32 + fg * 8) ^ ((fr & 7) << 3);
            short8 af[4], bw[4];
#pragma unroll
            for (int mi = 0; mi < 4; ++mi)
                af[mi] = *(const short8*)&As[(wr * 64 + mi * 16 + fr) * 64 + coff];
#pragma unroll
            for (int nj = 0; nj < 4; ++nj)
                bw[nj] = *(const short8*)&Bs[(wc * 64 + nj * 16 + fr) * 64 + coff];
#pragma unroll
            for (int mi = 0; mi < 4; ++mi)
#pragma unroll
                for (int nj = 0; nj < 4; ++nj)
                    acc[mi][nj] = __builtin_amdgcn_mfma_f32_16x16x32_bf16(
                        af[mi], bw[nj], acc[mi][nj], 0, 0, 0);
        }
    }

    if (z < 2) {  // natural bf16 [m][n]
#pragma unroll
        for (int mi = 0; mi < 4; ++mi)
#pragma unroll
            for (int nj = 0; nj < 4; ++nj) {
                const int n = bcol + wc * 64 + nj * 16 + fr;
#pragma unroll
                for (int r = 0; r < 4; ++r) {
                    const int m = brow + wr * 64 + mi * 16 + fg * 4 + r;
                    C[(size_t)m * D_MODEL + n] = f2bf(acc[mi][nj][r]);
                }
            }
    } else {  // V^T: [b][n][s], s = m % 2048, b = m / 2048
#pragma unroll
        for (int mi = 0; mi < 4; ++mi)
#pragma unroll
            for (int nj = 0; nj < 4; ++nj) {
                const int n = bcol + wc * 64 + nj * 16 + fr;
                const int m0 = brow + wr * 64 + mi * 16 + fg * 4;
                ushort4v o4;
#pragma unroll
                for (int r = 0; r < 4; ++r) o4[r] = f2bf(acc[mi][nj][r]);
                *(ushort4v*)&C[((size_t)(m0 >> 11) << 21) + (size_t)n * SEQ + (m0 & 2047)] = o4;
            }
    }
}

// ---------------------------------------------------------------------------
// Output GEMM (NT, f32 out): 128x64 tile, BK=64, dbuf (from R3, unchanged).
// ---------------------------------------------------------------------------
__global__ __launch_bounds__(256)
void gemm_out(const ushort_t* __restrict__ A, const ushort_t* __restrict__ B,
              float* __restrict__ C) {
    __shared__ __align__(16) ushort_t As[2][128 * 64];
    __shared__ __align__(16) ushort_t Bs[2][64 * 64];

    const int tid = threadIdx.x;
    const int lane = tid & 63;
    const int wid = tid >> 6;
    const int wr = wid >> 1, wc = wid & 1;
    const int brow = blockIdx.y * 128;
    const int bcol = blockIdx.x * 64;

    const int lrow = lane >> 3;
    const int loff = ((lane & 7) ^ lrow) * 8;

    const ushort_t* aSrc[4];
    const ushort_t* bSrc[2];
#pragma unroll
    for (int i = 0; i < 4; ++i)
        aSrc[i] = A + (size_t)(brow + (wid * 4 + i) * 8 + lrow) * D_MODEL + loff;
#pragma unroll
    for (int i = 0; i < 2; ++i)
        bSrc[i] = B + (size_t)(bcol + (wid * 2 + i) * 8 + lrow) * D_MODEL + loff;

    f32x4 acc[4][2];
#pragma unroll
    for (int i = 0; i < 4; ++i)
#pragma unroll
        for (int j = 0; j < 2; ++j) acc[i][j] = {0.f, 0.f, 0.f, 0.f};

    const int fr = lane & 15, fg = lane >> 4;

#pragma unroll
    for (int i = 0; i < 4; ++i) GLDS16(aSrc[i], As[0] + (wid * 4 + i) * 512);
#pragma unroll
    for (int i = 0; i < 2; ++i) GLDS16(bSrc[i], Bs[0] + (wid * 2 + i) * 512);

    int cur = 0;
    for (int k0 = 0; k0 < D_MODEL; k0 += 64) {
        __syncthreads();
        if (k0 + 64 < D_MODEL) {
#pragma unroll
            for (int i = 0; i < 4; ++i)
                GLDS16(aSrc[i] + k0 + 64, As[cur ^ 1] + (wid * 4 + i) * 512);
#pragma unroll
            for (int i = 0; i < 2; ++i)
                GLDS16(bSrc[i] + k0 + 64, Bs[cur ^ 1] + (wid * 2 + i) * 512);
        }
#pragma unroll
        for (int ks = 0; ks < 2; ++ks) {
            const int coff = (ks * 32 + fg * 8) ^ ((fr & 7) << 3);
            short8 af[4], bw[2];
#pragma unroll
            for (int mi = 0; mi < 4; ++mi)
                af[mi] = *(const short8*)&As[cur][(wr * 64 + mi * 16 + fr) * 64 + coff];
#pragma unroll
            for (int nj = 0; nj < 2; ++nj)
                bw[nj] = *(const short8*)&Bs[cur][(wc * 32 + nj * 16 + fr) * 64 + coff];
#pragma unroll
            for (int mi = 0; mi < 4; ++mi)
#pragma unroll
                for (int nj = 0; nj < 2; ++nj)
                    acc[mi][nj] = __builtin_amdgcn_mfma_f32_16x16x32_bf16(
                        af[mi], bw[nj], acc[mi][nj], 0, 0, 0);
        }
        cur ^= 1;
    }

#pragma unroll
    for (int mi = 0; mi < 4; ++mi)
#pragma unroll
        for (int nj = 0; nj < 2; ++nj) {
            const int n = bcol + wc * 32 + nj * 16 + fr;
#pragma unroll
            for (int r = 0; r < 4; ++r) {
                const int m = brow + wr * 64 + mi * 16 + fg * 4 + r;
                C[(size_t)m * D_MODEL + n] = acc[mi][nj][r];
            }
        }
}

// ---------------------------------------------------------------------------
// bf16 MFMA flash attention. QBLK=128 (4 waves x 32 q-rows), KVBLK=64 dbuf.
// Swapped QK^T; softmax in log2-scaled domain (exp arg = 1 fma); defer-max
// THR=8; P->bf16 via v_cvt_pk_bf16_f32; per-lane partial l reduced at end.
// LDS: K 16K dbuf + V 16K dbuf + P/Q 16K = 48 KB. Grid 512 = 2 blocks/CU.
// ---------------------------------------------------------------------------
__global__ __launch_bounds__(256)
void attn_mfma(const ushort_t* __restrict__ Qp, const ushort_t* __restrict__ Kp,
               const ushort_t* __restrict__ VT, ushort_t* __restrict__ Ap) {
    __shared__ __align__(16) ushort_t Ks[2][64 * 64];   // 16 KB
    __shared__ __align__(16) ushort_t Vs[2][64 * 64];   // 16 KB (d-major)
    __shared__ __align__(16) ushort_t Ps[4 * 32 * 64];  // 16 KB: Q staging, then P

    const int tid = threadIdx.x;
    const int lane = tid & 63;
    const int wid = tid >> 6;
    const int bid = blockIdx.x;
    const int qt = bid & 15;
    const int h = (bid >> 4) & 15;
    const int b = bid >> 8;

    const int lrow = lane >> 3;
    const int loff = ((lane & 7) ^ lrow) * 8;
    const int fr = lane & 15, fg = lane >> 4;

    const int m0 = b * SEQ + qt * 128;  // global q-row base

    // ---- stage Q (own wave's 32 rows -> own Ps region) + K0/V0 ----
#pragma unroll
    for (int j = 0; j < 4; ++j) {
        const ushort_t* qS =
            Qp + (size_t)(m0 + wid * 32 + j * 8 + lrow) * D_MODEL + h * 64 + loff;
        GLDS16(qS, Ps + (wid * 32 + j * 8) * 64);
    }
    const ushort_t* kS[2];
    const ushort_t* vS[2];
#pragma unroll
    for (int j = 0; j < 2; ++j) {
        const int cr = (wid * 2 + j) * 8 + lrow;
        kS[j] = Kp + (size_t)(b * SEQ + cr) * D_MODEL + h * 64 + loff;
        vS[j] = VT + ((size_t)b << 21) + (size_t)(h * 64 + cr) * SEQ + loff;
        GLDS16(kS[j], Ks[0] + (wid * 2 + j) * 512);
        GLDS16(vS[j], Vs[0] + (wid * 2 + j) * 512);
        kS[j] += 64 * D_MODEL;
        vS[j] += 64;
    }
    __syncthreads();  // Q/K0/V0 landed

    short8 aq[2][2];
#pragma unroll
    for (int qh = 0; qh < 2; ++qh)
#pragma unroll
        for (int ks = 0; ks < 2; ++ks)
            aq[qh][ks] = *(const short8*)&Ps[(wid * 32 + qh * 16 + fr) * 64 +
                                             ((ks * 32 + fg * 8) ^ ((fr & 7) << 3))];

    f32x4 accO[2][4];
#pragma unroll
    for (int qh = 0; qh < 2; ++qh)
#pragma unroll
        for (int nd = 0; nd < 4; ++nd) accO[qh][nd] = {0.f, 0.f, 0.f, 0.f};
    float m_s[2] = {-INFINITY, -INFINITY};  // running max, log2-scaled domain
    float l_p[2] = {0.f, 0.f};              // per-lane partial denominator

    const float CEXP = 0.18033688011112042f;  // log2(e) / sqrt(64)

    int cur = 0;
    for (int kt = 0; kt < SEQ / 64; ++kt) {
        __syncthreads();  // tile-kt staging landed; all waves done with buf^1
        if (kt + 1 < SEQ / 64) {
#pragma unroll
            for (int j = 0; j < 2; ++j) {
                GLDS16(kS[j], Ks[cur ^ 1] + (wid * 2 + j) * 512);
                GLDS16(vS[j], Vs[cur ^ 1] + (wid * 2 + j) * 512);
                kS[j] += 64 * D_MODEL;
                vS[j] += 64;
            }
        }

        // ---- swapped scores: lane holds q-col fr (x2 qh), keys n*16+fg*4+r ----
        f32x4 accS[2][4];
#pragma unroll
        for (int qh = 0; qh < 2; ++qh)
#pragma unroll
            for (int n = 0; n < 4; ++n) accS[qh][n] = {0.f, 0.f, 0.f, 0.f};
#pragma unroll
        for (int ks = 0; ks < 2; ++ks) {
            const int coff = (ks * 32 + fg * 8) ^ ((fr & 7) << 3);
            short8 ak[4];
#pragma unroll
            for (int n = 0; n < 4; ++n)
                ak[n] = *(const short8*)&Ks[cur][(n * 16 + fr) * 64 + coff];
#pragma unroll
            for (int qh = 0; qh < 2; ++qh)
#pragma unroll
                for (int n = 0; n < 4; ++n)
                    accS[qh][n] = __builtin_amdgcn_mfma_f32_16x16x32_bf16(
                        ak[n], aq[qh][ks], accS[qh][n], 0, 0, 0);
        }

        // ---- softmax (log2-scaled, defer-max) + P write ----
#pragma unroll
        for (int qh = 0; qh < 2; ++qh) {
            float mx = accS[qh][0][0];
#pragma unroll
            for (int n = 0; n < 4; ++n)
#pragma unroll
                for (int r = 0; r < 4; ++r) mx = fmaxf(mx, accS[qh][n][r]);
            mx = fmaxf(mx, __shfl_xor(mx, 16));
            mx = fmaxf(mx, __shfl_xor(mx, 32));
            const float cand = mx * CEXP;
            if (__any(cand > m_s[qh] + 8.f)) {
                const float mnew = fmaxf(m_s[qh], cand);
                const float al = __builtin_amdgcn_exp2f(m_s[qh] - mnew);
                m_s[qh] = mnew;
                l_p[qh] *= al;
#pragma unroll
                for (int r = 0; r < 4; ++r) {
                    const float ar = __shfl(al, (lane & 48) | (fg * 4 + r));
#pragma unroll
                    for (int nd = 0; nd < 4; ++nd) accO[qh][nd][r] *= ar;
                }
            }
            float ps = 0.f;
            const float nm = -m_s[qh];
#pragma unroll
            for (int n = 0; n < 4; ++n)
#pragma unroll
                for (int r = 0; r < 4; ++r) {
                    const float p = __builtin_amdgcn_exp2f(fmaf(accS[qh][n][r], CEXP, nm));
                    accS[qh][n][r] = p;
                    ps += p;
                }
            l_p[qh] += ps;

            const int pbase = wid * 2048 + (qh * 16 + fr) * 64;
#pragma unroll
            for (int n = 0; n < 4; ++n) {
                uint2v pw2 = {cvtpk(accS[qh][n][0], accS[qh][n][1]),
                              cvtpk(accS[qh][n][2], accS[qh][n][3])};
                const int w = (n * 4 + fg) ^ (fr & 14);
                *(uint2v*)&Ps[pbase + w * 4] = pw2;
            }
        }

        // ---- PV: O[q][d] += P[q][k] V^T[d][k] ----
#pragma unroll
        for (int ks = 0; ks < 2; ++ks) {
            const int coff = (ks * 32 + fg * 8) ^ ((fr & 7) << 3);
            short8 bv[4];
#pragma unroll
            for (int nd = 0; nd < 4; ++nd)
                bv[nd] = *(const short8*)&Vs[cur][(nd * 16 + fr) * 64 + coff];
#pragma unroll
            for (int qh = 0; qh < 2; ++qh) {
                const int p0 = (ks * 8 + 2 * fg) ^ (fr & 14);
                short8 ap = *(const short8*)&Ps[wid * 2048 + (qh * 16 + fr) * 64 + p0 * 4];
#pragma unroll
                for (int nd = 0; nd < 4; ++nd)
                    accO[qh][nd] = __builtin_amdgcn_mfma_f32_16x16x32_bf16(
                        ap, bv[nd], accO[qh][nd], 0, 0, 0);
            }
        }
        cur ^= 1;
    }

    // ---- epilogue: reduce partial l across the 4 fg-lanes, write bf16 ----
#pragma unroll
    for (int qh = 0; qh < 2; ++qh) {
        float lt = l_p[qh];
        lt += __shfl_xor(lt, 16);
        lt += __shfl_xor(lt, 32);
#pragma unroll
        for (int r = 0; r < 4; ++r) {
            const float lq = __shfl(lt, (lane & 48) | (fg * 4 + r));
            const float inv = 1.0f / lq;
            const int row = m0 + wid * 32 + qh * 16 + fg * 4 + r;
#pragma unroll
            for (int nd = 0; nd < 4; ++nd)
                Ap[(size_t)row * D_MODEL + h * 64 + nd * 16 + fr] =
                    f2bf(accO[qh][nd][r] * inv);
        }
    }
}

// ---------------------------------------------------------------------------
extern "C" void kernel_launch(void* const* d_in, const int* in_sizes, int n_in,
                              void* d_out, int out_size, void* d_ws, size_t ws_size,
                              hipStream_t stream) {
    const float* query = (const float*)d_in[0];
    const float* key   = (const float*)d_in[1];
    const float* value = (const float*)d_in[2];
    const float* W_q   = (const float*)d_in[3];
    const float* W_k   = (const float*)d_in[4];
    const float* W_v   = (const float*)d_in[5];
    const float* W_o   = (const float*)d_in[6];
    float* out = (float*)d_out;

    ushort_t* ws = (ushort_t*)d_ws;
    ushort_t* Xq = ws;                               // 3 bf16 input planes
    ushort_t* Wb = ws + 3 * (size_t)PLANE;           // 4 bf16 weights
    ushort_t* Qp = ws + 4 * (size_t)PLANE;           // Q proj (natural)
    ushort_t* Kp = Qp + (size_t)PLANE;               // K proj (natural)
    ushort_t* VT = Kp + (size_t)PLANE;               // V proj (transposed)
    ushort_t* Ap = VT + (size_t)PLANE;               // attention out (natural)
    // total 8 * PLANE * 2B = 67.1 MB

    cvt_all<<<8192, 256, 0, stream>>>(query, key, value, W_q, W_k, W_v, W_o, Xq);

    dim3 g3(D_MODEL / 128, MROWS / 128, 3);  // (8, 32, 3) = 768 blocks
    gemm3<<<g3, 256, 0, stream>>>(Xq, Wb, Qp);

    attn_mfma<<<512, 256, 0, stream>>>(Qp, Kp, VT, Ap);

    dim3 go(D_MODEL / 64, MROWS / 128);  // (16, 32) = 512 blocks
    gemm_out<<<go, 256, 0, stream>>>(Ap, Wb + 3 * (size_t)WELEM, out);
}

// Round 5
// 136.977 us; speedup vs baseline: 8.7277x; 1.0286x over previous
//
#include <hip/hip_runtime.h>
#include <math.h>

typedef unsigned short ushort_t;
typedef __attribute__((ext_vector_type(8))) short short8;
typedef __attribute__((ext_vector_type(4))) float f32x4;
typedef __attribute__((ext_vector_type(4))) unsigned short ushort4v;
typedef __attribute__((ext_vector_type(2))) unsigned int uint2v;

#define D_MODEL 1024
#define SEQ 2048
#define MROWS 4096
#define PLANE (MROWS * D_MODEL)    /* 4194304 elems */
#define WELEM (D_MODEL * D_MODEL)  /* 1048576 elems */

static __device__ __forceinline__ ushort_t f2bf(float f) {
    unsigned u = __builtin_bit_cast(unsigned, f);
    return (ushort_t)((u + 0x7fffu + ((u >> 16) & 1u)) >> 16);
}
static __device__ __forceinline__ unsigned cvtpk(float lo, float hi) {
    unsigned r;
    asm("v_cvt_pk_bf16_f32 %0, %1, %2" : "=v"(r) : "v"(lo), "v"(hi));
    return r;
}

// async global->LDS, 16B per lane; LDS dest = wave-uniform base + lane*16
#define GLDS16(gp, lp)                                                         \
    __builtin_amdgcn_global_load_lds(                                          \
        (const __attribute__((address_space(1))) void*)(gp),                   \
        (__attribute__((address_space(3))) void*)(lp), 16, 0, 0)

// ---------------------------------------------------------------------------
// fp32 -> bf16: all 7 tensors in one launch.
// blocks 0..6143: q/k/v (2048 each); 6144..8191: w0..w3 (512 each)
// ---------------------------------------------------------------------------
__global__ __launch_bounds__(256)
void cvt_all(const float* __restrict__ q, const float* __restrict__ k,
             const float* __restrict__ v, const float* __restrict__ w0,
             const float* __restrict__ w1, const float* __restrict__ w2,
             const float* __restrict__ w3, ushort_t* __restrict__ dst) {
    int blk = blockIdx.x;
    const float* s;
    size_t base;
    if (blk < 6144) {
        const int p = blk >> 11;
        s = (p == 0) ? q : (p == 1) ? k : v;
        base = (size_t)p * PLANE;
        blk &= 2047;
    } else {
        const int p = (blk - 6144) >> 9;
        s = (p == 0) ? w0 : (p == 1) ? w1 : (p == 2) ? w2 : w3;
        base = 3 * (size_t)PLANE + (size_t)p * WELEM;
        blk = (blk - 6144) & 511;
    }
    const int i = (blk * 256 + threadIdx.x) * 8;
    float4 a = *(const float4*)(s + i);
    float4 bb = *(const float4*)(s + i + 4);
    short8 o;
    o[0] = (short)f2bf(a.x); o[1] = (short)f2bf(a.y);
    o[2] = (short)f2bf(a.z); o[3] = (short)f2bf(a.w);
    o[4] = (short)f2bf(bb.x); o[5] = (short)f2bf(bb.y);
    o[6] = (short)f2bf(bb.z); o[7] = (short)f2bf(bb.w);
    *(short8*)(dst + base + i) = o;
}

// ---------------------------------------------------------------------------
// Projection GEMM x3 in one launch (z = 0:Q, 1:K, 2:V-transposed).
// m97 structure: 128x128 tile, BK=64, 4 waves (2x2, each 64x64),
// single-buffer LDS (32 KB) + 2 barriers per K-step, 3 blocks/CU.
// ---------------------------------------------------------------------------
__global__ __launch_bounds__(256)
void gemm3(const ushort_t* __restrict__ Xq, const ushort_t* __restrict__ Wb,
           ushort_t* __restrict__ Cb) {
    __shared__ __align__(16) ushort_t As[128 * 64];  // 16 KB
    __shared__ __align__(16) ushort_t Bs[128 * 64];  // 16 KB

    const int z = blockIdx.z;
    const ushort_t* A = Xq + (size_t)z * PLANE;
    const ushort_t* B = Wb + (size_t)z * WELEM;
    ushort_t* C = Cb + (size_t)z * PLANE;

    const int tid = threadIdx.x;
    const int lane = tid & 63;
    const int wid = tid >> 6;
    const int wr = wid >> 1, wc = wid & 1;
    const int brow = blockIdx.y * 128;
    const int bcol = blockIdx.x * 128;

    const int lrow = lane >> 3;
    const int loff = ((lane & 7) ^ lrow) * 8;  // pre-swizzled source offset

    const ushort_t* aS[4];
    const ushort_t* bS[4];
#pragma unroll
    for (int i = 0; i < 4; ++i) {
        aS[i] = A + (size_t)(brow + wid * 32 + i * 8 + lrow) * D_MODEL + loff;
        bS[i] = B + (size_t)(bcol + wid * 32 + i * 8 + lrow) * D_MODEL + loff;
    }

    f32x4 acc[4][4];
#pragma unroll
    for (int i = 0; i < 4; ++i)
#pragma unroll
        for (int j = 0; j < 4; ++j) acc[i][j] = {0.f, 0.f, 0.f, 0.f};

    const int fr = lane & 15, fg = lane >> 4;

    for (int k0 = 0; k0 < D_MODEL; k0 += 64) {
        __syncthreads();  // prior frag reads done
#pragma unroll
        for (int i = 0; i < 4; ++i) {
            GLDS16(aS[i] + k0, As + (wid * 32 + i * 8) * 64);
            GLDS16(bS[i] + k0, Bs + (wid * 32 + i * 8) * 64);
        }
        __syncthreads();  // staging landed (vmcnt drained before barrier)
#pragma unroll
        for (int ks = 0; ks < 2; ++ks) {
            const int coff = (ks * 32 + fg * 8) ^ ((fr & 7) << 3);
            short8 af[4], bw[4];
#pragma unroll
            for (int mi = 0; mi < 4; ++mi)
                af[mi] = *(const short8*)&As[(wr * 64 + mi * 16 + fr) * 64 + coff];
#pragma unroll
            for (int nj = 0; nj < 4; ++nj)
                bw[nj] = *(const short8*)&Bs[(wc * 64 + nj * 16 + fr) * 64 + coff];
#pragma unroll
            for (int mi = 0; mi < 4; ++mi)
#pragma unroll
                for (int nj = 0; nj < 4; ++nj)
                    acc[mi][nj] = __builtin_amdgcn_mfma_f32_16x16x32_bf16(
                        af[mi], bw[nj], acc[mi][nj], 0, 0, 0);
        }
    }

    if (z < 2) {  // natural bf16 [m][n]
#pragma unroll
        for (int mi = 0; mi < 4; ++mi)
#pragma unroll
            for (int nj = 0; nj < 4; ++nj) {
                const int n = bcol + wc * 64 + nj * 16 + fr;
#pragma unroll
                for (int r = 0; r < 4; ++r) {
                    const int m = brow + wr * 64 + mi * 16 + fg * 4 + r;
                    C[(size_t)m * D_MODEL + n] = f2bf(acc[mi][nj][r]);
                }
            }
    } else {  // V^T: [b][n][s], s = m % 2048, b = m / 2048
#pragma unroll
        for (int mi = 0; mi < 4; ++mi)
#pragma unroll
            for (int nj = 0; nj < 4; ++nj) {
                const int n = bcol + wc * 64 + nj * 16 + fr;
                const int m0 = brow + wr * 64 + mi * 16 + fg * 4;
                ushort4v o4;
#pragma unroll
                for (int r = 0; r < 4; ++r) o4[r] = f2bf(acc[mi][nj][r]);
                *(ushort4v*)&C[((size_t)(m0 >> 11) << 21) + (size_t)n * SEQ + (m0 & 2047)] = o4;
            }
    }
}

// ---------------------------------------------------------------------------
// Output GEMM (NT, f32 out): 128x64 tile, BK=64, dbuf.
// ---------------------------------------------------------------------------
__global__ __launch_bounds__(256)
void gemm_out(const ushort_t* __restrict__ A, const ushort_t* __restrict__ B,
              float* __restrict__ C) {
    __shared__ __align__(16) ushort_t As[2][128 * 64];
    __shared__ __align__(16) ushort_t Bs[2][64 * 64];

    const int tid = threadIdx.x;
    const int lane = tid & 63;
    const int wid = tid >> 6;
    const int wr = wid >> 1, wc = wid & 1;
    const int brow = blockIdx.y * 128;
    const int bcol = blockIdx.x * 64;

    const int lrow = lane >> 3;
    const int loff = ((lane & 7) ^ lrow) * 8;

    const ushort_t* aSrc[4];
    const ushort_t* bSrc[2];
#pragma unroll
    for (int i = 0; i < 4; ++i)
        aSrc[i] = A + (size_t)(brow + (wid * 4 + i) * 8 + lrow) * D_MODEL + loff;
#pragma unroll
    for (int i = 0; i < 2; ++i)
        bSrc[i] = B + (size_t)(bcol + (wid * 2 + i) * 8 + lrow) * D_MODEL + loff;

    f32x4 acc[4][2];
#pragma unroll
    for (int i = 0; i < 4; ++i)
#pragma unroll
        for (int j = 0; j < 2; ++j) acc[i][j] = {0.f, 0.f, 0.f, 0.f};

    const int fr = lane & 15, fg = lane >> 4;

#pragma unroll
    for (int i = 0; i < 4; ++i) GLDS16(aSrc[i], As[0] + (wid * 4 + i) * 512);
#pragma unroll
    for (int i = 0; i < 2; ++i) GLDS16(bSrc[i], Bs[0] + (wid * 2 + i) * 512);

    int cur = 0;
    for (int k0 = 0; k0 < D_MODEL; k0 += 64) {
        __syncthreads();
        if (k0 + 64 < D_MODEL) {
#pragma unroll
            for (int i = 0; i < 4; ++i)
                GLDS16(aSrc[i] + k0 + 64, As[cur ^ 1] + (wid * 4 + i) * 512);
#pragma unroll
            for (int i = 0; i < 2; ++i)
                GLDS16(bSrc[i] + k0 + 64, Bs[cur ^ 1] + (wid * 2 + i) * 512);
        }
#pragma unroll
        for (int ks = 0; ks < 2; ++ks) {
            const int coff = (ks * 32 + fg * 8) ^ ((fr & 7) << 3);
            short8 af[4], bw[2];
#pragma unroll
            for (int mi = 0; mi < 4; ++mi)
                af[mi] = *(const short8*)&As[cur][(wr * 64 + mi * 16 + fr) * 64 + coff];
#pragma unroll
            for (int nj = 0; nj < 2; ++nj)
                bw[nj] = *(const short8*)&Bs[cur][(wc * 32 + nj * 16 + fr) * 64 + coff];
#pragma unroll
            for (int mi = 0; mi < 4; ++mi)
#pragma unroll
                for (int nj = 0; nj < 2; ++nj)
                    acc[mi][nj] = __builtin_amdgcn_mfma_f32_16x16x32_bf16(
                        af[mi], bw[nj], acc[mi][nj], 0, 0, 0);
        }
        cur ^= 1;
    }

#pragma unroll
    for (int mi = 0; mi < 4; ++mi)
#pragma unroll
        for (int nj = 0; nj < 2; ++nj) {
            const int n = bcol + wc * 32 + nj * 16 + fr;
#pragma unroll
            for (int r = 0; r < 4; ++r) {
                const int m = brow + wr * 64 + mi * 16 + fg * 4 + r;
                C[(size_t)m * D_MODEL + n] = acc[mi][nj][r];
            }
        }
}

// ---------------------------------------------------------------------------
// bf16 MFMA flash attention. QBLK=128 as 8 waves x 16 q-rows (512 thr),
// KVBLK=64 dbuf. 2 blocks/CU -> 16 waves/CU = 4 waves/SIMD: one wave's
// softmax VALU overlaps other waves' MFMA. s_setprio(1) around MFMA
// clusters (T5; pays at this wave diversity). Swapped QK^T; log2-domain
// softmax; defer-max THR=8; P->bf16 via v_cvt_pk_bf16_f32.
// LDS: K 16K dbuf + V 16K dbuf + P/Q 16K = 48 KB.
// ---------------------------------------------------------------------------
__global__ __launch_bounds__(512)
void attn_mfma(const ushort_t* __restrict__ Qp, const ushort_t* __restrict__ Kp,
               const ushort_t* __restrict__ VT, ushort_t* __restrict__ Ap) {
    __shared__ __align__(16) ushort_t Ks[2][64 * 64];   // 16 KB
    __shared__ __align__(16) ushort_t Vs[2][64 * 64];   // 16 KB (d-major)
    __shared__ __align__(16) ushort_t Ps[8 * 16 * 64];  // 16 KB: Q staging, then P

    const int tid = threadIdx.x;
    const int lane = tid & 63;
    const int wid = tid >> 6;  // 0..7
    const int bid = blockIdx.x;
    const int qt = bid & 15;
    const int h = (bid >> 4) & 15;
    const int b = bid >> 8;

    const int lrow = lane >> 3;
    const int loff = ((lane & 7) ^ lrow) * 8;
    const int fr = lane & 15, fg = lane >> 4;

    const int m0 = b * SEQ + qt * 128;  // global q-row base

    // ---- stage Q (own wave's 16 rows -> own Ps region) + K0/V0 ----
#pragma unroll
    for (int j = 0; j < 2; ++j) {
        const ushort_t* qS =
            Qp + (size_t)(m0 + wid * 16 + j * 8 + lrow) * D_MODEL + h * 64 + loff;
        GLDS16(qS, Ps + (wid * 16 + j * 8) * 64);
    }
    // K/V: each of the 8 waves stages 8 rows (one GLDS16 each)
    const ushort_t* kS =
        Kp + (size_t)(b * SEQ + wid * 8 + lrow) * D_MODEL + h * 64 + loff;
    const ushort_t* vS =
        VT + ((size_t)b << 21) + (size_t)(h * 64 + wid * 8 + lrow) * SEQ + loff;
    GLDS16(kS, Ks[0] + wid * 512);
    GLDS16(vS, Vs[0] + wid * 512);
    kS += 64 * D_MODEL;
    vS += 64;
    __syncthreads();  // Q/K0/V0 landed

    short8 aq[2];
#pragma unroll
    for (int ks = 0; ks < 2; ++ks)
        aq[ks] = *(const short8*)&Ps[(wid * 16 + fr) * 64 +
                                     ((ks * 32 + fg * 8) ^ ((fr & 7) << 3))];

    f32x4 accO[4];
#pragma unroll
    for (int nd = 0; nd < 4; ++nd) accO[nd] = {0.f, 0.f, 0.f, 0.f};
    float m_s = -INFINITY;  // running max, log2-scaled domain
    float l_p = 0.f;        // per-lane partial denominator

    const float CEXP = 0.18033688011112042f;  // log2(e) / sqrt(64)
    const int pbase = wid * 1024 + fr * 64;

    int cur = 0;
    for (int kt = 0; kt < SEQ / 64; ++kt) {
        __syncthreads();  // tile-kt staging landed; all waves done with buf^1
        if (kt + 1 < SEQ / 64) {
            GLDS16(kS, Ks[cur ^ 1] + wid * 512);
            GLDS16(vS, Vs[cur ^ 1] + wid * 512);
            kS += 64 * D_MODEL;
            vS += 64;
        }

        // ---- swapped scores: lane holds q-col fr, keys n*16+fg*4+r ----
        f32x4 accS[4];
#pragma unroll
        for (int n = 0; n < 4; ++n) accS[n] = {0.f, 0.f, 0.f, 0.f};
        __builtin_amdgcn_s_setprio(1);
#pragma unroll
        for (int ks = 0; ks < 2; ++ks) {
            const int coff = (ks * 32 + fg * 8) ^ ((fr & 7) << 3);
#pragma unroll
            for (int n = 0; n < 4; ++n) {
                short8 ak = *(const short8*)&Ks[cur][(n * 16 + fr) * 64 + coff];
                accS[n] = __builtin_amdgcn_mfma_f32_16x16x32_bf16(ak, aq[ks],
                                                                  accS[n], 0, 0, 0);
            }
        }
        __builtin_amdgcn_s_setprio(0);

        // ---- softmax (log2-scaled, defer-max) ----
        float mx = accS[0][0];
#pragma unroll
        for (int n = 0; n < 4; ++n)
#pragma unroll
            for (int r = 0; r < 4; ++r) mx = fmaxf(mx, accS[n][r]);
        mx = fmaxf(mx, __shfl_xor(mx, 16));
        mx = fmaxf(mx, __shfl_xor(mx, 32));
        const float cand = mx * CEXP;
        if (__any(cand > m_s + 8.f)) {
            const float mnew = fmaxf(m_s, cand);
            const float al = __builtin_amdgcn_exp2f(m_s - mnew);
            m_s = mnew;
            l_p *= al;
#pragma unroll
            for (int r = 0; r < 4; ++r) {
                const float ar = __shfl(al, (lane & 48) | (fg * 4 + r));
#pragma unroll
                for (int nd = 0; nd < 4; ++nd) accO[nd][r] *= ar;
            }
        }
        float ps = 0.f;
        const float nm = -m_s;
#pragma unroll
        for (int n = 0; n < 4; ++n)
#pragma unroll
            for (int r = 0; r < 4; ++r) {
                const float p = __builtin_amdgcn_exp2f(fmaf(accS[n][r], CEXP, nm));
                accS[n][r] = p;
                ps += p;
            }
        l_p += ps;

        // ---- P -> bf16 -> own wave's LDS region ----
#pragma unroll
        for (int n = 0; n < 4; ++n) {
            uint2v pw2 = {cvtpk(accS[n][0], accS[n][1]),
                          cvtpk(accS[n][2], accS[n][3])};
            const int w = (n * 4 + fg) ^ (fr & 14);
            *(uint2v*)&Ps[pbase + w * 4] = pw2;
        }

        // ---- PV: O[q][d] += P[q][k] V^T[d][k] ----
        __builtin_amdgcn_s_setprio(1);
#pragma unroll
        for (int ks = 0; ks < 2; ++ks) {
            const int coff = (ks * 32 + fg * 8) ^ ((fr & 7) << 3);
            const int p0 = (ks * 8 + 2 * fg) ^ (fr & 14);
            short8 ap = *(const short8*)&Ps[pbase + p0 * 4];
#pragma unroll
            for (int nd = 0; nd < 4; ++nd) {
                short8 bv = *(const short8*)&Vs[cur][(nd * 16 + fr) * 64 + coff];
                accO[nd] = __builtin_amdgcn_mfma_f32_16x16x32_bf16(ap, bv,
                                                                   accO[nd], 0, 0, 0);
            }
        }
        __builtin_amdgcn_s_setprio(0);
        cur ^= 1;
    }

    // ---- epilogue: reduce partial l across fg-lanes, write bf16 ----
    float lt = l_p;
    lt += __shfl_xor(lt, 16);
    lt += __shfl_xor(lt, 32);
#pragma unroll
    for (int r = 0; r < 4; ++r) {
        const float lq = __shfl(lt, (lane & 48) | (fg * 4 + r));
        const float inv = 1.0f / lq;
        const int row = m0 + wid * 16 + fg * 4 + r;
#pragma unroll
        for (int nd = 0; nd < 4; ++nd)
            Ap[(size_t)row * D_MODEL + h * 64 + nd * 16 + fr] =
                f2bf(accO[nd][r] * inv);
    }
}

// ---------------------------------------------------------------------------
extern "C" void kernel_launch(void* const* d_in, const int* in_sizes, int n_in,
                              void* d_out, int out_size, void* d_ws, size_t ws_size,
                              hipStream_t stream) {
    const float* query = (const float*)d_in[0];
    const float* key   = (const float*)d_in[1];
    const float* value = (const float*)d_in[2];
    const float* W_q   = (const float*)d_in[3];
    const float* W_k   = (const float*)d_in[4];
    const float* W_v   = (const float*)d_in[5];
    const float* W_o   = (const float*)d_in[6];
    float* out = (float*)d_out;

    ushort_t* ws = (ushort_t*)d_ws;
    ushort_t* Xq = ws;                               // 3 bf16 input planes
    ushort_t* Wb = ws + 3 * (size_t)PLANE;           // 4 bf16 weights
    ushort_t* Qp = ws + 4 * (size_t)PLANE;           // Q proj (natural)
    ushort_t* Kp = Qp + (size_t)PLANE;               // K proj (natural)
    ushort_t* VT = Kp + (size_t)PLANE;               // V proj (transposed)
    ushort_t* Ap = VT + (size_t)PLANE;               // attention out (natural)
    // total 8 * PLANE * 2B = 67.1 MB

    cvt_all<<<8192, 256, 0, stream>>>(query, key, value, W_q, W_k, W_v, W_o, Xq);

    dim3 g3(D_MODEL / 128, MROWS / 128, 3);  // (8, 32, 3) = 768 blocks
    gemm3<<<g3, 256, 0, stream>>>(Xq, Wb, Qp);

    attn_mfma<<<512, 512, 0, stream>>>(Qp, Kp, VT, Ap);

    dim3 go(D_MODEL / 64, MROWS / 128);  // (16, 32) = 512 blocks
    gemm_out<<<go, 256, 0, stream>>>(Ap, Wb + 3 * (size_t)WELEM, out);
}